// Round 8
// baseline (206.617 us; speedup 1.0000x reference)
//
#include <hip/hip_runtime.h>
#include <stdint.h>

#define B_SZ  4096
#define HEADS 16
#define HD    64
#define M_SZ  4096
#define K_IN  1024
#define SW    72    // padded LDS row stride (f16 elems)
#define LOG2E 1.44269504088896f

typedef _Float16 f16;
typedef f16  f16x4 __attribute__((ext_vector_type(4)));
typedef f16  f16x8 __attribute__((ext_vector_type(8)));
typedef float f32x4 __attribute__((ext_vector_type(4)));

union U8 { uint4 u4; f16x8 h8; unsigned int ui[4]; unsigned short us[8]; };

__device__ __forceinline__ unsigned short f2h(float f) {
    _Float16 h = (_Float16)f;
    return __builtin_bit_cast(unsigned short, h);
}
__device__ __forceinline__ f16x8 ldsv8(const unsigned short* p) {
    U8 u; u.u4 = *reinterpret_cast<const uint4*>(p); return u.h8;
}

#if __has_builtin(__builtin_amdgcn_exp2f)
#define EXP2F(x) __builtin_amdgcn_exp2f(x)
#else
#define EXP2F(x) __expf((x) * 0.6931471805599453f)
#endif

#if __has_builtin(__builtin_amdgcn_sched_barrier)
#define SCHED_FENCE() __builtin_amdgcn_sched_barrier(0)
#else
#define SCHED_FENCE()
#endif

// async global -> LDS: lane i's 16 B land at ldsbase + i*16
__device__ __forceinline__ void gload_lds16(const void* g, void* l) {
    __builtin_amdgcn_global_load_lds(
        (const __attribute__((address_space(1))) void*)g,
        (__attribute__((address_space(3))) void*)l, 16, 0, 0);
}

// ---------------------------------------------------------------------------
// Kernel 1: normalize memories, emit fragment-ordered F[h][tile64][chunk16][lane][8]
// chunks 0..7  (gs=g*2+s): QK A-frag (16x16x32), PERMUTED m:
//   elem = Mn[m_phys(g, lane&15)][d = s*32 + (lane>>4)*8 + j]
//   m_phys(g,r) = 32*(g>>1) + (r>>2)*8 + 4*(g&1) + (r&3)
// chunks 8..15 (c2=p*4+n): PV B-frag (16x16x32), physical m:
//   elem = Mn[32*p + (lane>>4)*8 + j][d = n*16 + (lane&15)]
// After QK+exp, lane's regs {g=2p,r0..3; g=2p+1,r0..3} are exactly the PV A-frag.
// ---------------------------------------------------------------------------
__global__ __launch_bounds__(256) void k_prep_mem(const float* __restrict__ mem,
                                                  unsigned short* __restrict__ F) {
    __shared__ float part[64][4];
    __shared__ float scale[64];
    __shared__ unsigned short Tn[64 * SW];

    const int h  = blockIdx.y;
    const int tl = blockIdx.x;
    const int m0 = tl * 64;
    const int tid = threadIdx.x;
    const int r = tid >> 2;
    const int c = tid & 3;

    const float* src = mem + ((size_t)(h * M_SZ + m0 + r)) * HD + c * 16;
    float v[16];
    float ss = 0.f;
#pragma unroll
    for (int i = 0; i < 4; i++) {
        float4 f = reinterpret_cast<const float4*>(src)[i];
        v[4*i+0] = f.x; v[4*i+1] = f.y; v[4*i+2] = f.z; v[4*i+3] = f.w;
        ss += f.x*f.x + f.y*f.y + f.z*f.z + f.w*f.w;
    }
    part[r][c] = ss;
    __syncthreads();
    if (tid < 64) {
        float s = part[tid][0] + part[tid][1] + part[tid][2] + part[tid][3];
        scale[tid] = rsqrtf(s);
    }
    __syncthreads();
    const float sc = scale[r];

    U8 a, b;
#pragma unroll
    for (int i = 0; i < 8; i++) { a.us[i] = f2h(v[i] * sc); b.us[i] = f2h(v[8 + i] * sc); }
    *reinterpret_cast<uint4*>(&Tn[r * SW + c * 16])     = a.u4;
    *reinterpret_cast<uint4*>(&Tn[r * SW + c * 16 + 8]) = b.u4;
    __syncthreads();

    const int w = tid >> 6, lane = tid & 63;
    const int l15 = lane & 15, quad = lane >> 4;
    unsigned short* Fd = F + ((size_t)(h * 64 + tl) * 16) * 512;

    // QK A-frag chunks (permuted m)
#pragma unroll
    for (int i = 0; i < 2; i++) {
        const int ch = w * 2 + i, g = ch >> 1, s = ch & 1;
        const int mp = 32 * (g >> 1) + ((l15 >> 2) * 8) + 4 * (g & 1) + (l15 & 3);
        uint4 vv = *reinterpret_cast<const uint4*>(&Tn[mp * SW + s * 32 + quad * 8]);
        *reinterpret_cast<uint4*>(Fd + ch * 512 + lane * 8) = vv;
    }
    // PV B-frag chunks (physical m)
#pragma unroll
    for (int i = 0; i < 2; i++) {
        const int c2 = w * 2 + i, p = c2 >> 2, n = c2 & 3;
        U8 u;
#pragma unroll
        for (int j = 0; j < 8; j++)
            u.us[j] = Tn[(32 * p + quad * 8 + j) * SW + n * 16 + l15];
        *reinterpret_cast<uint4*>(Fd + (8 + c2) * 512 + lane * 8) = u.u4;
    }
}

// ---------------------------------------------------------------------------
// Kernel 2: q = x @ Wq^T directly from f32 (convert during staging), 128x128
// tile, fused per-head L2 norm (2 heads per block), prescaled by log2(e).
// grid 256: n-strip = bx&7 (one per XCD -> W strip L2-resident), q-tile = bx>>3.
// ---------------------------------------------------------------------------
__global__ __launch_bounds__(256) void k_qproj(const float* __restrict__ x,
                                               const float* __restrict__ Wq,
                                               unsigned short* __restrict__ qn) {
    __shared__ unsigned short sbuf[2 * 128 * SW];
    unsigned short* As = sbuf;
    unsigned short* Bs = sbuf + 128 * SW;

    const int bx = blockIdx.x;
    const int n0 = (bx & 7) * 128;
    const int b0 = (bx >> 3) * 128;
    const int t = threadIdx.x;
    const int w = t >> 6, lane = t & 63;
    const int l15 = lane & 15, quad = lane >> 4;

    f32x4 acc[2][8] = {};   // [qg][g]: rows w*32+qg*16.., cols g*16..

    const int sr = t >> 1, sk = (t & 1) * 32;
    for (int kb = 0; kb < K_IN; kb += 64) {
        __syncthreads();
        {
            const float* px = x  + (size_t)(b0 + sr) * K_IN + kb + sk;
            const float* pw = Wq + (size_t)(n0 + sr) * K_IN + kb + sk;
            uint4 ox[4], ow[4];
#pragma unroll
            for (int i = 0; i < 4; i++) {
                float4 f0 = reinterpret_cast<const float4*>(px)[2*i];
                float4 f1 = reinterpret_cast<const float4*>(px)[2*i+1];
                U8 u;
                u.us[0]=f2h(f0.x); u.us[1]=f2h(f0.y); u.us[2]=f2h(f0.z); u.us[3]=f2h(f0.w);
                u.us[4]=f2h(f1.x); u.us[5]=f2h(f1.y); u.us[6]=f2h(f1.z); u.us[7]=f2h(f1.w);
                ox[i] = u.u4;
                float4 g0 = reinterpret_cast<const float4*>(pw)[2*i];
                float4 g1 = reinterpret_cast<const float4*>(pw)[2*i+1];
                U8 v;
                v.us[0]=f2h(g0.x); v.us[1]=f2h(g0.y); v.us[2]=f2h(g0.z); v.us[3]=f2h(g0.w);
                v.us[4]=f2h(g1.x); v.us[5]=f2h(g1.y); v.us[6]=f2h(g1.z); v.us[7]=f2h(g1.w);
                ow[i] = v.u4;
            }
#pragma unroll
            for (int i = 0; i < 4; i++) {
                *reinterpret_cast<uint4*>(&As[sr * SW + sk + i * 8]) = ox[i];
                *reinterpret_cast<uint4*>(&Bs[sr * SW + sk + i * 8]) = ow[i];
            }
        }
        __syncthreads();

#pragma unroll
        for (int s = 0; s < 2; s++) {
            f16x8 af[2];
#pragma unroll
            for (int qg = 0; qg < 2; qg++)
                af[qg] = ldsv8(&As[(w * 32 + qg * 16 + l15) * SW + s * 32 + quad * 8]);
#pragma unroll
            for (int g = 0; g < 8; g++) {
                f16x8 bf_ = ldsv8(&Bs[(g * 16 + l15) * SW + s * 32 + quad * 8]);
#pragma unroll
                for (int qg = 0; qg < 2; qg++)
                    acc[qg][g] = __builtin_amdgcn_mfma_f32_16x16x32_f16(af[qg], bf_, acc[qg][g], 0, 0, 0);
            }
        }
    }

    // per-head L2 norm: cols g0..3 = head 2*(bx&7), g4..7 = head 2*(bx&7)+1
    __syncthreads();
    unsigned short* Ct = sbuf;   // 128 x 136
#pragma unroll
    for (int qg = 0; qg < 2; qg++) {
        float s0[4], s1[4];
#pragma unroll
        for (int r = 0; r < 4; r++) {
            float a = 0.f, b = 0.f;
#pragma unroll
            for (int g = 0; g < 4; g++) { a += acc[qg][g][r] * acc[qg][g][r];
                                          b += acc[qg][g+4][r] * acc[qg][g+4][r]; }
            s0[r] = a; s1[r] = b;
        }
#pragma unroll
        for (int mask = 1; mask <= 8; mask <<= 1)
#pragma unroll
            for (int r = 0; r < 4; r++) { s0[r] += __shfl_xor(s0[r], mask, 64);
                                          s1[r] += __shfl_xor(s1[r], mask, 64); }
#pragma unroll
        for (int r = 0; r < 4; r++) {
            float i0 = rsqrtf(s0[r]) * LOG2E;
            float i1 = rsqrtf(s1[r]) * LOG2E;
            const int row = w * 32 + qg * 16 + quad * 4 + r;
#pragma unroll
            for (int g = 0; g < 4; g++) {
                Ct[row * 136 + g * 16 + l15]      = f2h(acc[qg][g][r] * i0);
                Ct[row * 136 + 64 + g * 16 + l15] = f2h(acc[qg][g+4][r] * i1);
            }
        }
    }
    __syncthreads();

    // FIX (round-7 bug): each thread owns 64 cols -> 8 uint4 stores, not 4.
    const int row = t >> 1, half = (t & 1) * 64;
    unsigned short* dq = qn + (size_t)(b0 + row) * 1024 + n0 + half;
#pragma unroll
    for (int i = 0; i < 8; i++)
        reinterpret_cast<uint4*>(dq)[i] = *reinterpret_cast<const uint4*>(&Ct[row * 136 + half + i * 8]);
}

// ---------------------------------------------------------------------------
// Kernel 3: fused attention. grid 512 (128 q x 1 head), 4 waves x 32 q (qg=2).
// 128-m iterations: 32 KB tile, double-buffered (64 KB LDS), 1 barrier/iter.
// ALL 32 fragments loaded to named regs, then sched_barrier(0) pins them
// before compute -> no per-MFMA LDS latency exposure (round-6 failure mode).
// ---------------------------------------------------------------------------
__global__ __launch_bounds__(256, 2) void k_attn(const unsigned short* __restrict__ qn,
                                                 const unsigned short* __restrict__ F,
                                                 float* __restrict__ out) {
    __shared__ unsigned short buf[2][16384];   // 2 x 32 KB

    const int b = blockIdx.x;
    const int h  = 2 * (b & 7) + (b >> 8);     // XCD k serves heads {2k, 2k+1}
    const int b0 = ((b >> 3) & 31) * 128;
    const int t = threadIdx.x;
    const int w = t >> 6, lane = t & 63;
    const int l15 = lane & 15, quad = lane >> 4;

    // Q as B-operand of 16x16x32: lane holds Q[q=l15][d = s*32 + quad*8 + j]
    f16x8 qf[2][2];
#pragma unroll
    for (int qg = 0; qg < 2; qg++)
#pragma unroll
        for (int s = 0; s < 2; s++) {
            U8 u;
            u.u4 = *reinterpret_cast<const uint4*>(
                qn + (size_t)(b0 + w * 32 + qg * 16 + l15) * 1024 + h * 64 + s * 32 + quad * 8);
            qf[qg][s] = u.h8;
        }

    const unsigned short* Fh = F + (size_t)h * 64 * 8192;

    // prologue: stage first 128-m pair (32 chunks); each wave 8 chunks
#pragma unroll
    for (int i = 0; i < 8; i++) {
        const int ch = w * 8 + i;
        gload_lds16(Fh + ch * 512 + lane * 8, &buf[0][ch * 512]);
    }

    f32x4 accO[2][4] = {};
    float lsum[2] = {0.f, 0.f};

    for (int it = 0; it < 32; ++it) {
        __syncthreads();   // drains vmcnt -> buf[it&1] staged; orders buffer reuse
        const int cur = it & 1;

        if (it + 1 < 32) {   // prefetch next 32 KB into the other buffer
            const unsigned short* gn = Fh + (size_t)(it + 1) * 16384;
#pragma unroll
            for (int i = 0; i < 8; i++) {
                const int ch = w * 8 + i;
                gload_lds16(gn + ch * 512 + lane * 8, &buf[cur ^ 1][ch * 512]);
            }
        }

        const unsigned short* lb = buf[cur];
        f16x8 am[2][8], bw[2][8];
#pragma unroll
        for (int sub = 0; sub < 2; sub++) {
#pragma unroll
            for (int ch = 0; ch < 8; ch++)
                am[sub][ch] = ldsv8(&lb[sub * 8192 + ch * 512 + lane * 8]);
#pragma unroll
            for (int ch = 0; ch < 8; ch++)
                bw[sub][ch] = ldsv8(&lb[sub * 8192 + (8 + ch) * 512 + lane * 8]);
        }
        SCHED_FENCE();   // pin: all 32 ds_reads issue before any compute

#pragma unroll
        for (int sub = 0; sub < 2; sub++) {
#pragma unroll
            for (int qg = 0; qg < 2; qg++) {
#pragma unroll
                for (int p = 0; p < 2; p++) {
                    f32x4 s0 = {0.f, 0.f, 0.f, 0.f}, s1 = {0.f, 0.f, 0.f, 0.f};
                    s0 = __builtin_amdgcn_mfma_f32_16x16x32_f16(am[sub][4*p+0], qf[qg][0], s0, 0, 0, 0);
                    s0 = __builtin_amdgcn_mfma_f32_16x16x32_f16(am[sub][4*p+1], qf[qg][1], s0, 0, 0, 0);
                    s1 = __builtin_amdgcn_mfma_f32_16x16x32_f16(am[sub][4*p+2], qf[qg][0], s1, 0, 0, 0);
                    s1 = __builtin_amdgcn_mfma_f32_16x16x32_f16(am[sub][4*p+3], qf[qg][1], s1, 0, 0, 0);

                    float p0 = EXP2F(s0[0]), p1 = EXP2F(s0[1]), p2 = EXP2F(s0[2]), p3 = EXP2F(s0[3]);
                    float p4 = EXP2F(s1[0]), p5 = EXP2F(s1[1]), p6 = EXP2F(s1[2]), p7 = EXP2F(s1[3]);
                    lsum[qg] += ((p0 + p1) + (p2 + p3)) + ((p4 + p5) + (p6 + p7));

                    U8 pu;
#if __has_builtin(__builtin_amdgcn_cvt_pkrtz)
                    pu.ui[0] = __builtin_bit_cast(unsigned int, __builtin_amdgcn_cvt_pkrtz(p0, p1));
                    pu.ui[1] = __builtin_bit_cast(unsigned int, __builtin_amdgcn_cvt_pkrtz(p2, p3));
                    pu.ui[2] = __builtin_bit_cast(unsigned int, __builtin_amdgcn_cvt_pkrtz(p4, p5));
                    pu.ui[3] = __builtin_bit_cast(unsigned int, __builtin_amdgcn_cvt_pkrtz(p6, p7));
#else
                    pu.us[0]=f2h(p0); pu.us[1]=f2h(p1); pu.us[2]=f2h(p2); pu.us[3]=f2h(p3);
                    pu.us[4]=f2h(p4); pu.us[5]=f2h(p5); pu.us[6]=f2h(p6); pu.us[7]=f2h(p7);
#endif
                    // pu.h8 == PV A-frag A[q=l15][k=quad*8+j] for m-block p (by construction)
#pragma unroll
                    for (int n = 0; n < 4; n++)
                        accO[qg][n] = __builtin_amdgcn_mfma_f32_16x16x32_f16(pu.h8, bw[sub][p * 4 + n], accO[qg][n], 0, 0, 0);
                }
            }
        }
    }

    // epilogue: reduce lsum over quads (same l15), normalize, store
#pragma unroll
    for (int qg = 0; qg < 2; qg++) {
        float s = lsum[qg];
        s += __shfl_xor(s, 16, 64);
        s += __shfl_xor(s, 32, 64);
        float inv = 8.0f / s;    // sqrt(HEAD_DIM) = 8
#pragma unroll
        for (int r = 0; r < 4; r++) {
            float iv = __shfl(inv, quad * 4 + r, 64);
            float* po = out + (size_t)(b0 + w * 32 + qg * 16 + quad * 4 + r) * 1024 + h * 64;
#pragma unroll
            for (int n = 0; n < 4; n++)
                po[n * 16 + l15] = accO[qg][n][r] * iv;
        }
    }
}

// ---------------------------------------------------------------------------
extern "C" void kernel_launch(void* const* d_in, const int* in_sizes, int n_in,
                              void* d_out, int out_size, void* d_ws, size_t ws_size,
                              hipStream_t stream) {
    (void)in_sizes; (void)n_in; (void)out_size; (void)ws_size;
    const float* x   = (const float*)d_in[0];
    const float* Wq  = (const float*)d_in[1];
    const float* mem = (const float*)d_in[2];
    float* out = (float*)d_out;

    unsigned short* qn = (unsigned short*)d_ws;        // 8 MB
    unsigned short* F  = qn + (size_t)B_SZ * 1024;     // 16 MB (frag-ordered) -> 24 MB total

    k_prep_mem<<<dim3(64, 16), 256, 0, stream>>>(mem, F);
    k_qproj   <<<256, 256, 0, stream>>>(x, Wq, qn);
    k_attn    <<<512, 256, 0, stream>>>(qn, F, out);
}

// Round 9
// 175.320 us; speedup vs baseline: 1.1785x; 1.1785x over previous
//
#include <hip/hip_runtime.h>
#include <stdint.h>

#define B_SZ  4096
#define HEADS 16
#define HD    64
#define M_SZ  4096
#define K_IN  1024
#define SW    72    // padded LDS row stride (f16 elems)
#define LOG2E 1.44269504088896f

typedef _Float16 f16;
typedef f16  f16x4 __attribute__((ext_vector_type(4)));
typedef f16  f16x8 __attribute__((ext_vector_type(8)));
typedef float f32x4 __attribute__((ext_vector_type(4)));

union U8 { uint4 u4; f16x8 h8; unsigned int ui[4]; unsigned short us[8]; };

__device__ __forceinline__ unsigned short f2h(float f) {
    _Float16 h = (_Float16)f;
    return __builtin_bit_cast(unsigned short, h);
}
__device__ __forceinline__ f16x8 ldsv8(const unsigned short* p) {
    U8 u; u.u4 = *reinterpret_cast<const uint4*>(p); return u.h8;
}

#if __has_builtin(__builtin_amdgcn_exp2f)
#define EXP2F(x) __builtin_amdgcn_exp2f(x)
#else
#define EXP2F(x) __expf((x) * 0.6931471805599453f)
#endif

// async global -> LDS: lane i's 16 B land at ldsbase + i*16
__device__ __forceinline__ void gload_lds16(const void* g, void* l) {
    __builtin_amdgcn_global_load_lds(
        (const __attribute__((address_space(1))) void*)g,
        (__attribute__((address_space(3))) void*)l, 16, 0, 0);
}

// ---------------------------------------------------------------------------
// Kernel 0: f32 -> f16 conversion of x and Wq (one pass).  [round-6 verbatim]
// ---------------------------------------------------------------------------
__global__ __launch_bounds__(256) void k_conv(const float* __restrict__ x,
                                              const float* __restrict__ Wq,
                                              unsigned short* __restrict__ xh,
                                              unsigned short* __restrict__ Wh) {
    const int b = blockIdx.x;
    const float* src;
    unsigned short* dst;
    size_t base;
    if (b < 2048) { src = x;  dst = xh; base = (size_t)b * 2048; }
    else          { src = Wq; dst = Wh; base = (size_t)(b - 2048) * 2048; }
    const size_t i = base + (size_t)threadIdx.x * 8;
    float4 f0 = reinterpret_cast<const float4*>(src + i)[0];
    float4 f1 = reinterpret_cast<const float4*>(src + i)[1];
    U8 u;
    u.us[0] = f2h(f0.x); u.us[1] = f2h(f0.y); u.us[2] = f2h(f0.z); u.us[3] = f2h(f0.w);
    u.us[4] = f2h(f1.x); u.us[5] = f2h(f1.y); u.us[6] = f2h(f1.z); u.us[7] = f2h(f1.w);
    *reinterpret_cast<uint4*>(dst + i) = u.u4;
}

// ---------------------------------------------------------------------------
// Kernel 1: normalize memories, emit fragment-ordered F[h][tile64][chunk16][lane][8]
// chunks 0..7  (gs=g*2+s): QK A-frag (16x16x32), PERMUTED m:
//   elem = Mn[m_phys(g, lane&15)][d = s*32 + (lane>>4)*8 + j]
//   m_phys(g,r) = 32*(g>>1) + (r>>2)*8 + 4*(g&1) + (r&3)
// chunks 8..15 (c2=p*4+n): PV B-frag (16x16x32), physical m:
//   elem = Mn[32*p + (lane>>4)*8 + j][d = n*16 + (lane&15)]
// After QK+exp, lane's regs {g=2p,r0..3; g=2p+1,r0..3} are exactly the PV A-frag.
// ---------------------------------------------------------------------------
__global__ __launch_bounds__(256) void k_prep_mem(const float* __restrict__ mem,
                                                  unsigned short* __restrict__ F) {
    __shared__ float part[64][4];
    __shared__ float scale[64];
    __shared__ unsigned short Tn[64 * SW];

    const int h  = blockIdx.y;
    const int tl = blockIdx.x;
    const int m0 = tl * 64;
    const int tid = threadIdx.x;
    const int r = tid >> 2;
    const int c = tid & 3;

    const float* src = mem + ((size_t)(h * M_SZ + m0 + r)) * HD + c * 16;
    float v[16];
    float ss = 0.f;
#pragma unroll
    for (int i = 0; i < 4; i++) {
        float4 f = reinterpret_cast<const float4*>(src)[i];
        v[4*i+0] = f.x; v[4*i+1] = f.y; v[4*i+2] = f.z; v[4*i+3] = f.w;
        ss += f.x*f.x + f.y*f.y + f.z*f.z + f.w*f.w;
    }
    part[r][c] = ss;
    __syncthreads();
    if (tid < 64) {
        float s = part[tid][0] + part[tid][1] + part[tid][2] + part[tid][3];
        scale[tid] = rsqrtf(s);
    }
    __syncthreads();
    const float sc = scale[r];

    U8 a, b;
#pragma unroll
    for (int i = 0; i < 8; i++) { a.us[i] = f2h(v[i] * sc); b.us[i] = f2h(v[8 + i] * sc); }
    *reinterpret_cast<uint4*>(&Tn[r * SW + c * 16])     = a.u4;
    *reinterpret_cast<uint4*>(&Tn[r * SW + c * 16 + 8]) = b.u4;
    __syncthreads();

    const int w = tid >> 6, lane = tid & 63;
    const int l15 = lane & 15, quad = lane >> 4;
    unsigned short* Fd = F + ((size_t)(h * 64 + tl) * 16) * 512;

    // QK A-frag chunks (permuted m)
#pragma unroll
    for (int i = 0; i < 2; i++) {
        const int ch = w * 2 + i, g = ch >> 1, s = ch & 1;
        const int mp = 32 * (g >> 1) + ((l15 >> 2) * 8) + 4 * (g & 1) + (l15 & 3);
        uint4 vv = *reinterpret_cast<const uint4*>(&Tn[mp * SW + s * 32 + quad * 8]);
        *reinterpret_cast<uint4*>(Fd + ch * 512 + lane * 8) = vv;
    }
    // PV B-frag chunks (physical m)
#pragma unroll
    for (int i = 0; i < 2; i++) {
        const int c2 = w * 2 + i, p = c2 >> 2, n = c2 & 3;
        U8 u;
#pragma unroll
        for (int j = 0; j < 8; j++)
            u.us[j] = Tn[(32 * p + quad * 8 + j) * SW + n * 16 + l15];
        *reinterpret_cast<uint4*>(Fd + (8 + c2) * 512 + lane * 8) = u.u4;
    }
}

// ---------------------------------------------------------------------------
// Kernel 2: q = xh @ Wh^T (f16 MFMA, 128x64 tile = one head), fused L2 norm,
// prescaled by log2(e). grid (32, 16) = 512 blocks -> 2 blocks/CU.
// [round-6 verbatim — measured-good config]
// ---------------------------------------------------------------------------
__global__ __launch_bounds__(256, 2) void k_qproj(const unsigned short* __restrict__ xh,
                                                  const unsigned short* __restrict__ Wh,
                                                  unsigned short* __restrict__ qn) {
    __shared__ unsigned short As[128 * SW];
    __shared__ unsigned short Bs[64 * SW];

    const int b0 = blockIdx.x * 128;
    const int n0 = blockIdx.y * 64;     // == h*64
    const int t = threadIdx.x;
    const int w = t >> 6, lane = t & 63;
    const int l15 = lane & 15, quad = lane >> 4;

    f32x4 acc[2][4] = {};

    for (int kb = 0; kb < K_IN; kb += 64) {
        __syncthreads();
        {
            const unsigned short* px = xh + (size_t)(b0 + (t >> 1)) * K_IN + kb + (t & 1) * 32;
            const unsigned short* pw = Wh + (size_t)(n0 + (t >> 2)) * K_IN + kb + (t & 3) * 16;
            uint4 av[4];
#pragma unroll
            for (int i = 0; i < 4; i++) av[i] = reinterpret_cast<const uint4*>(px)[i];
            uint4 bv[2];
#pragma unroll
            for (int i = 0; i < 2; i++) bv[i] = reinterpret_cast<const uint4*>(pw)[i];
#pragma unroll
            for (int i = 0; i < 4; i++)
                *reinterpret_cast<uint4*>(&As[(t >> 1) * SW + (t & 1) * 32 + i * 8]) = av[i];
#pragma unroll
            for (int i = 0; i < 2; i++)
                *reinterpret_cast<uint4*>(&Bs[(t >> 2) * SW + (t & 3) * 16 + i * 8]) = bv[i];
        }
        __syncthreads();

#pragma unroll
        for (int s = 0; s < 2; s++) {
            f16x8 af[2];
#pragma unroll
            for (int qg = 0; qg < 2; qg++)
                af[qg] = ldsv8(&As[(w * 32 + qg * 16 + l15) * SW + s * 32 + quad * 8]);
#pragma unroll
            for (int g = 0; g < 4; g++) {
                f16x8 bf_ = ldsv8(&Bs[(g * 16 + l15) * SW + s * 32 + quad * 8]);
#pragma unroll
                for (int qg = 0; qg < 2; qg++)
                    acc[qg][g] = __builtin_amdgcn_mfma_f32_16x16x32_f16(af[qg], bf_, acc[qg][g], 0, 0, 0);
            }
        }
    }

    __syncthreads();
    unsigned short* Ct = As;   // 128 x SW
#pragma unroll
    for (int qg = 0; qg < 2; qg++) {
        float ssq[4];
#pragma unroll
        for (int r = 0; r < 4; r++) {
            float s = 0.f;
#pragma unroll
            for (int g = 0; g < 4; g++) s += acc[qg][g][r] * acc[qg][g][r];
            ssq[r] = s;
        }
#pragma unroll
        for (int mask = 1; mask <= 8; mask <<= 1)
#pragma unroll
            for (int r = 0; r < 4; r++) ssq[r] += __shfl_xor(ssq[r], mask, 64);
#pragma unroll
        for (int r = 0; r < 4; r++) {
            float inv = rsqrtf(ssq[r]) * LOG2E;
#pragma unroll
            for (int g = 0; g < 4; g++)
                Ct[(w * 32 + qg * 16 + quad * 4 + r) * SW + g * 16 + l15] = f2h(acc[qg][g][r] * inv);
        }
    }
    __syncthreads();

    const int row = t >> 1, half = (t & 1) * 32;
    unsigned short* dq = qn + (size_t)(b0 + row) * 1024 + n0 + half;
#pragma unroll
    for (int i = 0; i < 4; i++)
        reinterpret_cast<uint4*>(dq)[i] = *reinterpret_cast<const uint4*>(&Ct[row * SW + half + i * 8]);
}

// ---------------------------------------------------------------------------
// Kernel 3: fused attention, SOFTWARE-PIPELINED. grid 512 (128 q x 1 head),
// 4 waves x 32 q (qg=2). 64-m tiles (16 KB), LDS double buffer (32 KB).
// Pipeline: PV(tile i) MFMAs interleaved with QK(tile i+1) MFMAs; pu (P frags)
// and bw (V frags) register-double-buffered across the barrier, so the exp
// chain of tile i+1 overlaps PV MFMAs of tile i.
// ---------------------------------------------------------------------------
__global__ __launch_bounds__(256, 2) void k_attn(const unsigned short* __restrict__ qn,
                                                 const unsigned short* __restrict__ F,
                                                 float* __restrict__ out) {
    __shared__ unsigned short buf[2][8192];   // 2 x 16 KB

    const int b = blockIdx.x;
    const int h  = 2 * (b & 7) + (b >> 8);    // XCD k serves heads {2k, 2k+1}
    const int b0 = ((b >> 3) & 31) * 128;
    const int t = threadIdx.x;
    const int w = t >> 6, lane = t & 63;
    const int l15 = lane & 15, quad = lane >> 4;

    // Q as B-operand of 16x16x32: lane holds Q[q=l15][d = s*32 + quad*8 + j]
    f16x8 qf[2][2];
#pragma unroll
    for (int qg = 0; qg < 2; qg++)
#pragma unroll
        for (int s = 0; s < 2; s++) {
            U8 u;
            u.u4 = *reinterpret_cast<const uint4*>(
                qn + (size_t)(b0 + w * 32 + qg * 16 + l15) * 1024 + h * 64 + s * 32 + quad * 8);
            qf[qg][s] = u.h8;
        }

    const unsigned short* Fh = F + (size_t)h * 64 * 8192;

    f32x4 accO[2][4] = {};
    float lsum[2] = {0.f, 0.f};

    // pipeline register state (double-buffered)
    f16x8 puA[2][2], puB[2][2];   // P A-frags [qg][p]
    f16x8 bwA[8],   bwB[8];       // V B-frags [p*4+n]

    // ---- prologue: stage tile 0, compute pu(0)/bw(0) into set A ----
#pragma unroll
    for (int i = 0; i < 4; i++) {
        const int ch = w * 4 + i;
        gload_lds16(Fh + ch * 512 + lane * 8, &buf[0][ch * 512]);
    }
    __syncthreads();
    {
        f16x8 am[8];
#pragma unroll
        for (int ch = 0; ch < 8; ch++) am[ch] = ldsv8(&buf[0][ch * 512 + lane * 8]);
#pragma unroll
        for (int ch = 0; ch < 8; ch++) bwA[ch] = ldsv8(&buf[0][(8 + ch) * 512 + lane * 8]);
        // stage tile 1 (buf[1]) while computing QK(0)
#pragma unroll
        for (int i = 0; i < 4; i++) {
            const int ch = w * 4 + i;
            gload_lds16(Fh + 8192 + ch * 512 + lane * 8, &buf[1][ch * 512]);
        }
#pragma unroll
        for (int g = 0; g < 4; g++) {
            const int qg = g >> 1, p = g & 1;
            f32x4 t0 = {0.f,0.f,0.f,0.f}, t1 = {0.f,0.f,0.f,0.f};
            t0 = __builtin_amdgcn_mfma_f32_16x16x32_f16(am[4*p+0], qf[qg][0], t0, 0, 0, 0);
            t0 = __builtin_amdgcn_mfma_f32_16x16x32_f16(am[4*p+1], qf[qg][1], t0, 0, 0, 0);
            t1 = __builtin_amdgcn_mfma_f32_16x16x32_f16(am[4*p+2], qf[qg][0], t1, 0, 0, 0);
            t1 = __builtin_amdgcn_mfma_f32_16x16x32_f16(am[4*p+3], qf[qg][1], t1, 0, 0, 0);
            float p0 = EXP2F(t0[0]), p1 = EXP2F(t0[1]), p2 = EXP2F(t0[2]), p3 = EXP2F(t0[3]);
            float p4 = EXP2F(t1[0]), p5 = EXP2F(t1[1]), p6 = EXP2F(t1[2]), p7 = EXP2F(t1[3]);
            lsum[qg] += ((p0 + p1) + (p2 + p3)) + ((p4 + p5) + (p6 + p7));
            U8 pu;
#if __has_builtin(__builtin_amdgcn_cvt_pkrtz)
            pu.ui[0] = __builtin_bit_cast(unsigned int, __builtin_amdgcn_cvt_pkrtz(p0, p1));
            pu.ui[1] = __builtin_bit_cast(unsigned int, __builtin_amdgcn_cvt_pkrtz(p2, p3));
            pu.ui[2] = __builtin_bit_cast(unsigned int, __builtin_amdgcn_cvt_pkrtz(p4, p5));
            pu.ui[3] = __builtin_bit_cast(unsigned int, __builtin_amdgcn_cvt_pkrtz(p6, p7));
#else
            pu.us[0]=f2h(p0); pu.us[1]=f2h(p1); pu.us[2]=f2h(p2); pu.us[3]=f2h(p3);
            pu.us[4]=f2h(p4); pu.us[5]=f2h(p5); pu.us[6]=f2h(p6); pu.us[7]=f2h(p7);
#endif
            puA[qg][p] = pu.h8;
        }
    }

    // ---- pipelined body: PV(tl) || QK(tl+1) ----
    auto body = [&](int tl, f16x8 (&puC)[2][2], f16x8 (&bwC)[8],
                            f16x8 (&puN)[2][2], f16x8 (&bwN)[8]) {
        __syncthreads();   // tile tl+1 staged; all waves done ds-reading buf[tl&1]
        const unsigned short* lb = buf[(tl + 1) & 1];
        f16x8 amn[8];
#pragma unroll
        for (int ch = 0; ch < 8; ch++) amn[ch] = ldsv8(&lb[ch * 512 + lane * 8]);
#pragma unroll
        for (int ch = 0; ch < 8; ch++) bwN[ch] = ldsv8(&lb[(8 + ch) * 512 + lane * 8]);
        if (tl + 2 < 64) {   // overwrite buf[tl&1] (tile tl frags already in regs)
            const unsigned short* gsrc = Fh + (size_t)(tl + 2) * 8192;
#pragma unroll
            for (int i = 0; i < 4; i++) {
                const int ch = w * 4 + i;
                gload_lds16(gsrc + ch * 512 + lane * 8, &buf[tl & 1][ch * 512]);
            }
        }

        f32x4 sa[4], sb[4];
        auto expPack = [&](int g) {
            const int qg = g >> 1, p = g & 1;
            float p0 = EXP2F(sa[g][0]), p1 = EXP2F(sa[g][1]), p2 = EXP2F(sa[g][2]), p3 = EXP2F(sa[g][3]);
            float p4 = EXP2F(sb[g][0]), p5 = EXP2F(sb[g][1]), p6 = EXP2F(sb[g][2]), p7 = EXP2F(sb[g][3]);
            lsum[qg] += ((p0 + p1) + (p2 + p3)) + ((p4 + p5) + (p6 + p7));
            U8 pu;
#if __has_builtin(__builtin_amdgcn_cvt_pkrtz)
            pu.ui[0] = __builtin_bit_cast(unsigned int, __builtin_amdgcn_cvt_pkrtz(p0, p1));
            pu.ui[1] = __builtin_bit_cast(unsigned int, __builtin_amdgcn_cvt_pkrtz(p2, p3));
            pu.ui[2] = __builtin_bit_cast(unsigned int, __builtin_amdgcn_cvt_pkrtz(p4, p5));
            pu.ui[3] = __builtin_bit_cast(unsigned int, __builtin_amdgcn_cvt_pkrtz(p6, p7));
#else
            pu.us[0]=f2h(p0); pu.us[1]=f2h(p1); pu.us[2]=f2h(p2); pu.us[3]=f2h(p3);
            pu.us[4]=f2h(p4); pu.us[5]=f2h(p5); pu.us[6]=f2h(p6); pu.us[7]=f2h(p7);
#endif
            puN[qg][p] = pu.h8;
        };

#pragma unroll
        for (int g = 0; g < 4; g++) {
            const int qg = g >> 1, p = g & 1;
            // QK group g of tile tl+1
            f32x4 t0 = {0.f,0.f,0.f,0.f}, t1 = {0.f,0.f,0.f,0.f};
            t0 = __builtin_amdgcn_mfma_f32_16x16x32_f16(amn[4*p+0], qf[qg][0], t0, 0, 0, 0);
            t0 = __builtin_amdgcn_mfma_f32_16x16x32_f16(amn[4*p+1], qf[qg][1], t0, 0, 0, 0);
            t1 = __builtin_amdgcn_mfma_f32_16x16x32_f16(amn[4*p+2], qf[qg][0], t1, 0, 0, 0);
            t1 = __builtin_amdgcn_mfma_f32_16x16x32_f16(amn[4*p+3], qf[qg][1], t1, 0, 0, 0);
            sa[g] = t0; sb[g] = t1;
            // PV group g of tile tl (independent of the QK above)
#pragma unroll
            for (int n = 0; n < 4; n++)
                accO[qg][n] = __builtin_amdgcn_mfma_f32_16x16x32_f16(puC[qg][p], bwC[p * 4 + n], accO[qg][n], 0, 0, 0);
            // exp of the PREVIOUS group (its QK results are long since ready)
            if (g >= 1) expPack(g - 1);
        }
        expPack(3);
    };

    for (int tt = 0; tt < 31; ++tt) {
        body(2 * tt,     puA, bwA, puB, bwB);
        body(2 * tt + 1, puB, bwB, puA, bwA);
    }
    body(62, puA, bwA, puB, bwB);

    // ---- epilogue: PV(63) from register set B, then normalize + store ----
#pragma unroll
    for (int g = 0; g < 4; g++) {
        const int qg = g >> 1, p = g & 1;
#pragma unroll
        for (int n = 0; n < 4; n++)
            accO[qg][n] = __builtin_amdgcn_mfma_f32_16x16x32_f16(puB[qg][p], bwB[p * 4 + n], accO[qg][n], 0, 0, 0);
    }

#pragma unroll
    for (int qg = 0; qg < 2; qg++) {
        float s = lsum[qg];
        s += __shfl_xor(s, 16, 64);
        s += __shfl_xor(s, 32, 64);
        float inv = 8.0f / s;    // sqrt(HEAD_DIM) = 8
#pragma unroll
        for (int r = 0; r < 4; r++) {
            float iv = __shfl(inv, quad * 4 + r, 64);
            float* po = out + (size_t)(b0 + w * 32 + qg * 16 + quad * 4 + r) * 1024 + h * 64;
#pragma unroll
            for (int n = 0; n < 4; n++)
                po[n * 16 + l15] = accO[qg][n][r] * iv;
        }
    }
}

// ---------------------------------------------------------------------------
extern "C" void kernel_launch(void* const* d_in, const int* in_sizes, int n_in,
                              void* d_out, int out_size, void* d_ws, size_t ws_size,
                              hipStream_t stream) {
    (void)in_sizes; (void)n_in; (void)out_size; (void)ws_size;
    const float* x   = (const float*)d_in[0];
    const float* Wq  = (const float*)d_in[1];
    const float* mem = (const float*)d_in[2];
    float* out = (float*)d_out;

    unsigned short* qn = (unsigned short*)d_ws;                 // 8 MB
    unsigned short* F  = qn + (size_t)B_SZ * 1024;              // 16 MB (frag-ordered)
    unsigned short* xh = F  + (size_t)HEADS * 64 * 16 * 512;    // 8 MB
    unsigned short* Wh = xh + (size_t)B_SZ * K_IN;              // 2 MB   (total 34 MB)

    k_conv    <<<2560, 256, 0, stream>>>(x, Wq, xh, Wh);
    k_prep_mem<<<dim3(64, 16), 256, 0, stream>>>(mem, F);
    k_qproj   <<<dim3(32, 16), 256, 0, stream>>>(xh, Wh, qn);
    k_attn    <<<512, 256, 0, stream>>>(qn, F, out);
}